// Round 13
// baseline (354.497 us; speedup 1.0000x reference)
//
#include <hip/hip_runtime.h>

#define NB 65536
#define NSTEP 128
#define HD 64
#define RB 1.05f
#define SCALE 2.8853900817779268f   // 2*log2(e)
#define TBLK 928          // uint4 per time-step in the ws blob (slots 0..NSTEP; slot NSTEP = u-weights)
#define OFF_A1 0          // 512 uint4 : SCALE*W1^T frags (pi-permuted rows)
#define OFF_A0 512        // 256 uint4 : SCALE*[W0^T; c0] frags (h1idx-permuted rows, c0 at k=3)
#define OFF_A2 768        // 128 uint4 : W2^T frags, ROW-REPLICATED (row 4q+j = W2 col j; j<3)
#define OFF_CB 896        // 32 uint4  : SCALE*c1 (64 f32, pi-permuted)

typedef __bf16 bf16x8 __attribute__((ext_vector_type(8)));
typedef float f32x4 __attribute__((ext_vector_type(4)));
typedef unsigned int uint;
typedef unsigned short ushort;

extern "C" __device__ float __ocml_native_exp2_f32(float);
#if __has_builtin(__builtin_amdgcn_exp2f)
#define EXP2(x) __builtin_amdgcn_exp2f(x)
#else
#define EXP2(x) __ocml_native_exp2_f32(x)
#endif

__device__ __forceinline__ float tanh_fast(float x) {
    float e2 = __expf(2.0f * x);
    return 1.0f - 2.0f * __builtin_amdgcn_rcpf(1.0f + e2);
}

// paired tanh on PRE-SCALED inputs z = 2*log2(e)*x; one v_rcp serves two tanh.
__device__ __forceinline__ void tanh2s(float za, float zb, float& ta, float& tb) {
    float ea = EXP2(za);
    float eb = EXP2(zb);
    float a1 = 1.0f + ea;
    float b1 = 1.0f + eb;
    float rpn = -2.0f * __builtin_amdgcn_rcpf(a1 * b1);
    ta = fmaf(b1, rpn, 1.0f);
    tb = fmaf(a1, rpn, 1.0f);
}

__device__ __forceinline__ void sincos_small(float x, float& s, float& c) {
    float x2 = x * x;
    s = fmaf(x2, fmaf(x2, 8.3333333e-3f, -0.16666667f), 1.0f) * x;
    c = fmaf(x2, fmaf(x2, fmaf(x2, -1.3888889e-3f, 4.1666668e-2f), -0.5f), 1.0f);
}

__device__ __forceinline__ uint pack_bf16_trunc(float a, float b) {
    return __builtin_amdgcn_perm(__float_as_uint(b), __float_as_uint(a), 0x07060302u);
}

__device__ __forceinline__ ushort bf16_rne(float f) {
    uint u = __float_as_uint(f);
    u += 0x7fffu + ((u >> 16) & 1u);
    return (ushort)(u >> 16);
}

// pi(I,s,j) == h1idx = (I>>1)*32 + s*8 + (I&1)*4 + j  (bijection on 0..63)

// ---- prep: A1 = SCALE*W1^T with pi-permuted rows (slot NSTEP = W1u) ----
__global__ __launch_bounds__(256) void prep_a1(const float* __restrict__ Wg1,
                                               const float* __restrict__ W1u,
                                               uint4* __restrict__ wsB) {
    int tid  = blockIdx.x * 256 + threadIdx.x;
    int lane = tid & 63;
    int I    = (tid >> 6) & 3;
    int kk   = (tid >> 8) & 1;
    int t    = tid >> 9;
    if (t > NSTEP) return;
    int rA   = lane & 15;
    int lrow = (I & 1) * 4 + (I >> 1) * 32 + (rA >> 2) * 8 + (rA & 3);
    int k0   = kk * 32 + ((lane >> 4) & 3) * 8;
    const float* base = (t < NSTEP) ? (Wg1 + (size_t)t * HD * HD) : W1u;
    const float* src  = base + (size_t)k0 * HD + lrow;
    ushort o[8];
#pragma unroll
    for (int e = 0; e < 8; e++) o[e] = bf16_rne(src[(size_t)e * HD] * SCALE);
    uint4 v;
    v.x = (uint)o[0] | ((uint)o[1] << 16);
    v.y = (uint)o[2] | ((uint)o[3] << 16);
    v.z = (uint)o[4] | ((uint)o[5] << 16);
    v.w = (uint)o[6] | ((uint)o[7] << 16);
    wsB[(size_t)t * TBLK + OFF_A1 + (kk * 4 + I) * 64 + lane] = v;
}

// ---- prep: A0 = SCALE*W0^T (h1idx-permuted rows); row k=3 holds SCALE*c0 ----
__global__ __launch_bounds__(256) void prep_a0(const float* __restrict__ Wg0,
                                               const float* __restrict__ bg0,
                                               const float* __restrict__ W0u,
                                               const float* __restrict__ b0u,
                                               uint4* __restrict__ wsB) {
    int tid  = blockIdx.x * 256 + threadIdx.x;
    int lane = tid & 63;
    int I    = (tid >> 6) & 3;
    int t    = tid >> 8;
    if (t > NSTEP) return;
    int m    = lane & 15;
    int kg   = (lane >> 4) & 3;
    int h    = (I >> 1) * 32 + (m >> 2) * 8 + (I & 1) * 4 + (m & 3);
    ushort o[8];
#pragma unroll
    for (int e = 0; e < 8; e++) {
        int k = kg * 8 + e;
        float v = 0.0f;
        if (k < 3)       v = SCALE * ((t < NSTEP) ? Wg0[((size_t)t * 3 + k) * HD + h]
                                                  : W0u[(size_t)k * HD + h]);
        else if (k == 3) v = SCALE * ((t < NSTEP) ? bg0[(size_t)t * HD + h] : b0u[h]);
        o[e] = bf16_rne(v);
    }
    uint4 v;
    v.x = (uint)o[0] | ((uint)o[1] << 16);
    v.y = (uint)o[2] | ((uint)o[3] << 16);
    v.z = (uint)o[4] | ((uint)o[5] << 16);
    v.w = (uint)o[6] | ((uint)o[7] << 16);
    wsB[(size_t)t * TBLK + OFF_A0 + I * 64 + lane] = v;
}

// ---- prep: A2 = W2^T ROW-REPLICATED (row 4q+j holds W2 col j; slot NSTEP = W2u at j=0) ----
__global__ __launch_bounds__(256) void prep_a2(const float* __restrict__ Wg2,
                                               const float* __restrict__ W2u,
                                               uint4* __restrict__ wsB) {
    int tid  = blockIdx.x * 256 + threadIdx.x;
    int lane = tid & 63;
    int kk   = (tid >> 6) & 1;
    int t    = tid >> 7;
    if (t > NSTEP) return;
    int row  = lane & 15;
    int j    = row & 3;
    int k0   = kk * 32 + ((lane >> 4) & 3) * 8;
    ushort o[8];
#pragma unroll
    for (int e = 0; e < 8; e++) {
        float v = 0.0f;
        if (j < 3) {
            if (t < NSTEP) v = Wg2[(size_t)t * HD * 3 + (size_t)(k0 + e) * 3 + j];
            else           v = (j == 0) ? W2u[k0 + e] : 0.0f;
        }
        o[e] = bf16_rne(v);
    }
    uint4 v;
    v.x = (uint)o[0] | ((uint)o[1] << 16);
    v.y = (uint)o[2] | ((uint)o[3] << 16);
    v.z = (uint)o[4] | ((uint)o[5] << 16);
    v.w = (uint)o[6] | ((uint)o[7] << 16);
    wsB[(size_t)t * TBLK + OFF_A2 + kk * 64 + lane] = v;
}

// ---- prep: SCALE*c1, pi-permuted (slot NSTEP = b1u) ----
__global__ __launch_bounds__(256) void prep_bias(const float* __restrict__ bg1,
                                                 const float* __restrict__ b1u,
                                                 uint4* __restrict__ wsB) {
    int tid = blockIdx.x * 256 + threadIdx.x;   // t*128 + i
    int i   = tid & 127;
    int t   = tid >> 7;
    if (t > NSTEP) return;
    int r   = i & 63;
    int pi  = ((r >> 4) & 1) * 4 + ((r >> 5) & 1) * 32 + ((r >> 2) & 3) * 8 + (r & 3);
    float* dst = (float*)(wsB + (size_t)t * TBLK + OFF_CB);
    float v = 0.0f;
    if (i < 64) v = SCALE * ((t < NSTEP) ? bg1[(size_t)t * HD + pi] : b1u[pi]);
    dst[i] = v;
}

// ---- the 3-GEMM MLP chain; B0 comes in PRE-PACKED (lo = bf16(x,y), hi = bf16(z,1)) ----
__device__ __forceinline__ f32x4 mlp_chain(uint b0lo, uint b0hi,
                                           const uint4* __restrict__ blob_t,
                                           int lane, int g16) {
    const f32x4 zero4 = (f32x4){0.f, 0.f, 0.f, 0.f};
    uint4 b0v;
    b0v.x = b0lo; b0v.y = b0hi; b0v.z = 0u; b0v.w = 0u;
    bf16x8 b0 = __builtin_bit_cast(bf16x8, b0v);

    uint4 a0v0 = {0u,0u,0u,0u}, a0v1 = {0u,0u,0u,0u}, a0v2 = {0u,0u,0u,0u}, a0v3 = {0u,0u,0u,0u};
    if (g16 == 0) {
        a0v0 = blob_t[OFF_A0 + 0 * 64 + lane];
        a0v1 = blob_t[OFF_A0 + 1 * 64 + lane];
        a0v2 = blob_t[OFF_A0 + 2 * 64 + lane];
        a0v3 = blob_t[OFF_A0 + 3 * 64 + lane];
    }
    f32x4 acc0[4];
    acc0[0] = __builtin_amdgcn_mfma_f32_16x16x32_bf16(__builtin_bit_cast(bf16x8, a0v0), b0, zero4, 0, 0, 0);
    acc0[1] = __builtin_amdgcn_mfma_f32_16x16x32_bf16(__builtin_bit_cast(bf16x8, a0v1), b0, zero4, 0, 0, 0);
    acc0[2] = __builtin_amdgcn_mfma_f32_16x16x32_bf16(__builtin_bit_cast(bf16x8, a0v2), b0, zero4, 0, 0, 0);
    acc0[3] = __builtin_amdgcn_mfma_f32_16x16x32_bf16(__builtin_bit_cast(bf16x8, a0v3), b0, zero4, 0, 0, 0);

    const float* c1p_t = (const float*)(blob_t + OFF_CB);
    f32x4 acc[4];
#pragma unroll
    for (int I = 0; I < 4; I++) {
        float4 cv = *(const float4*)(c1p_t + I * 16 + g16 * 4);
        acc[I] = (f32x4){cv.x, cv.y, cv.z, cv.w};
    }
#pragma unroll
    for (int kk = 0; kk < 2; kk++) {
        float t0, t1, t2, t3, t4, t5, t6, t7;
        tanh2s(acc0[kk * 2 + 0][0], acc0[kk * 2 + 0][1], t0, t1);
        tanh2s(acc0[kk * 2 + 0][2], acc0[kk * 2 + 0][3], t2, t3);
        tanh2s(acc0[kk * 2 + 1][0], acc0[kk * 2 + 1][1], t4, t5);
        tanh2s(acc0[kk * 2 + 1][2], acc0[kk * 2 + 1][3], t6, t7);
        uint4 bv;
        bv.x = pack_bf16_trunc(t0, t1);
        bv.y = pack_bf16_trunc(t2, t3);
        bv.z = pack_bf16_trunc(t4, t5);
        bv.w = pack_bf16_trunc(t6, t7);
        bf16x8 bf = __builtin_bit_cast(bf16x8, bv);
#pragma unroll
        for (int I = 0; I < 4; I++) {
            bf16x8 af = __builtin_bit_cast(bf16x8, blob_t[OFF_A1 + (kk * 4 + I) * 64 + lane]);
            acc[I] = __builtin_amdgcn_mfma_f32_16x16x32_bf16(af, bf, acc[I], 0, 0, 0);
        }
    }
    f32x4 acc2 = zero4;
#pragma unroll
    for (int half = 0; half < 2; half++) {
        float t0, t1, t2, t3, t4, t5, t6, t7;
        tanh2s(acc[2 * half + 0][0], acc[2 * half + 0][1], t0, t1);
        tanh2s(acc[2 * half + 0][2], acc[2 * half + 0][3], t2, t3);
        tanh2s(acc[2 * half + 1][0], acc[2 * half + 1][1], t4, t5);
        tanh2s(acc[2 * half + 1][2], acc[2 * half + 1][3], t6, t7);
        uint4 bv;
        bv.x = pack_bf16_trunc(t0, t1);
        bv.y = pack_bf16_trunc(t2, t3);
        bv.z = pack_bf16_trunc(t4, t5);
        bv.w = pack_bf16_trunc(t6, t7);
        bf16x8 bf = __builtin_bit_cast(bf16x8, bv);
        bf16x8 a2 = __builtin_bit_cast(bf16x8, blob_t[OFF_A2 + half * 64 + lane]);
        acc2 = __builtin_amdgcn_mfma_f32_16x16x32_bf16(a2, bf, acc2, 0, 0, 0);
    }
    return acc2;
}

// ---------------- producer: state recurrence + c2.w accumulation ----------------
__global__ __launch_bounds__(256) void sde_state(
    const float* __restrict__ xt0, const float* __restrict__ dBt,
    const float* __restrict__ bg2,
    uint4* __restrict__ xiw, float* __restrict__ c2w,
    float* __restrict__ out)
{
    int p = blockIdx.x * 256 + threadIdx.x;
    float xtx = xt0[p * 3 + 0];
    float xty = xt0[p * 3 + 1];
    float xtz = xt0[p * 3 + 2];
    float xix = xtx, xiy = xty, xiz = xtz;
    float g00 = 1.f, g01 = 0.f, g02 = 0.f;
    float g10 = 0.f, g11 = 1.f, g12 = 0.f;
    float g20 = 0.f, g21 = 0.f, g22 = 1.f;
    float c2wsum = 0.0f;

    float2 dBa = *(const float2*)(dBt + (size_t)p * 2);
    float2 dBb = *(const float2*)(dBt + ((size_t)NB + p) * 2);

#pragma unroll 1
    for (int t = 0; t < NSTEP; t++) {
        float d  = fmaf(xtx, xtx, fmaf(xty, xty, xtz * xtz));
        float rs = __builtin_amdgcn_rsqf(d);
        float uu = xtz * rs;
        uu = fminf(fmaxf(uu, -0.999999f), 0.999999f);
        float sa = -uu;
        float rho2 = fmaf(xtx, xtx, xty * xty);
        bool hasrho = rho2 > 0.0f;
        float rr = __builtin_amdgcn_rsqf(rho2);
        float cp = hasrho ? (xtx * rr) : 1.0f;
        float sp = hasrho ? (xty * rr) : 0.0f;
        float ca = hasrho ? (rho2 * rr * rs) : 1.4142135e-3f;
        float T00 = cp * ca, T01 = -sp, T02 = cp * sa;
        float T10 = sp * ca, T11 = cp,  T12 = sp * sa;
        float T20 = -sa,               T22 = ca;   // T21 = 0

        float M01 = fmaf(-sp, g00, cp * g01);
        float M11 = fmaf(-sp, g10, cp * g11);
        float M21 = fmaf(-sp, g20, cp * g21);
        float M02 = fmaf(g00, T02, fmaf(g01, T12, g02 * T22));
        float M12 = fmaf(g10, T02, fmaf(g11, T12, g12 * T22));
        float M22 = fmaf(g20, T02, fmaf(g21, T12, g22 * T22));

        float dB0 = dBa.x, dB1 = dBa.y;
        float w0 = fmaf(dB1, M01, -(dB0 * M02));
        float w1 = fmaf(dB1, M11, -(dB0 * M12));
        float w2v = fmaf(dB1, M21, -(dB0 * M22));

        // c2 . w accumulated here (consumer drops c2 entirely)
        const float* c2 = bg2 + (size_t)t * 3;
        c2wsum = fmaf(c2[0], w0, c2wsum);
        c2wsum = fmaf(c2[1], w1, c2wsum);
        c2wsum = fmaf(c2[2], w2v, c2wsum);

        uint4 xw;
        xw.x = pack_bf16_trunc(xix, xiy);
        xw.y = (__float_as_uint(xiz) >> 16) | ((uint)bf16_rne(w2v) << 16);
        xw.z = __float_as_uint(w0);
        xw.w = __float_as_uint(w1);
        xiw[(size_t)t * NB + p] = xw;

        float s0d, c0d, s1d, c1d;
        sincos_small(dB0, s0d, c0d);
        sincos_small(dB1, s1d, c1d);
        float dx30 = fmaf(c0d, c1d, -1.0f);
        float dx31 = c0d * s1d;
        float dx32 = -s0d;

        float dX0 = fmaf(T00, dx30, fmaf(T01, dx31, T02 * dx32));
        float dX1 = fmaf(T10, dx30, fmaf(T11, dx31, T12 * dx32));
        float dX2 = fmaf(T20, dx30, T22 * dx32);

        xtx += dX0; xty += dX1; xtz += dX2;

        float xi0 = xix + fmaf(g00, dX0, fmaf(g01, dX1, g02 * dX2));
        float xi1 = xiy + fmaf(g10, dX0, fmaf(g11, dX1, g12 * dX2));
        float xi2 = xiz + fmaf(g20, dX0, fmaf(g21, dX1, g22 * dX2));

        float ri2 = fmaf(xi0, xi0, fmaf(xi1, xi1, xi2 * xi2));
        float rs2 = __builtin_amdgcn_rsqf(ri2);
        float ri  = ri2 * rs2;
        bool outb = ri > RB;
        float n0 = xi0 * rs2, n1 = xi1 * rs2, n2 = xi2 * rs2;
        float coefs = outb ? (2.0f * (ri - RB)) : 0.0f;

        xix = fmaf(-coefs, n0, xi0);
        xiy = fmaf(-coefs, n1, xi1);
        xiz = fmaf(-coefs, n2, xi2);

        float mm0 = fmaf(n0, g00, fmaf(n1, g10, n2 * g20));
        float mm1 = fmaf(n0, g01, fmaf(n1, g11, n2 * g21));
        float mm2 = fmaf(n0, g02, fmaf(n1, g12, n2 * g22));
        float tw  = outb ? 2.0f : 0.0f;
        float tn0 = tw * n0, tn1 = tw * n1, tn2 = tw * n2;
        g00 = fmaf(-tn0, mm0, g00);
        g01 = fmaf(-tn0, mm1, g01);
        g02 = fmaf(-tn0, mm2, g02);
        g10 = fmaf(-tn1, mm0, g10);
        g11 = fmaf(-tn1, mm1, g11);
        g12 = fmaf(-tn1, mm2, g12);
        g20 = fmaf(-tn2, mm0, g20);
        g21 = fmaf(-tn2, mm1, g21);
        g22 = fmaf(-tn2, mm2, g22);

        dBa = dBb;
        int tn = (t + 2 < NSTEP) ? (t + 2) : (NSTEP - 1);
        dBb = *(const float2*)(dBt + ((size_t)tn * NB + p) * 2);
    }
    c2w[p] = c2wsum;
    out[NB + p] = fmaf(xix, xix, fmaf(xiy, xiy, xiz * xiz));
}

// ---------------- consumer: MLP over (chunk of 16 steps) x (16 particles/wave) ----------------
__global__ __launch_bounds__(256, 8) void sde_mlp(
    const float* __restrict__ xt0,
    const uint4* __restrict__ xiw,
    const uint4* __restrict__ wsB,
    const float* __restrict__ b2u,
    float* __restrict__ partial)
{
    const int tid  = threadIdx.x;
    const int lane = tid & 63;
    const int wv   = tid >> 6;
    const int g16  = (lane >> 4) & 3;
    const int l15  = lane & 15;
    const int blk  = blockIdx.x;            // 8192 blocks
    const int chunk = blk >> 10;            // 0..7
    const int p    = (blk & 1023) * 64 + wv * 16 + l15;

    float u_loc = 0.0f;
    if (chunk == 0) {
        // u_pre0 via the u-weight slot (t = NSTEP)
        float xx = xt0[p * 3 + 0];
        float xy = xt0[p * 3 + 1];
        float xz = xt0[p * 3 + 2];
        f32x4 a2 = mlp_chain(pack_bf16_trunc(xx, xy), pack_bf16_trunc(xz, 1.0f),
                             wsB + (size_t)NSTEP * TBLK, lane, g16);
        u_loc = a2[0] + b2u[0];
    }

#pragma unroll 1
    for (int s = 0; s < 16; s++) {
        int t = chunk * 16 + s;
        uint4 xw = xiw[(size_t)t * NB + p];
        uint b0hi = (xw.y & 0xFFFFu) | 0x3F800000u;        // bf16(z) | bf16(1.0)<<16
        float w2v = __uint_as_float(xw.y & 0xFFFF0000u);   // bf16(w2) (already in high half) -> f32
        f32x4 a2 = mlp_chain(xw.x, b0hi, wsB + (size_t)t * TBLK, lane, g16);
        u_loc = fmaf(a2[0], __uint_as_float(xw.z), u_loc);
        u_loc = fmaf(a2[1], __uint_as_float(xw.w), u_loc);
        u_loc = fmaf(a2[2], w2v, u_loc);
    }
    if (g16 == 0) partial[(size_t)chunk * NB + p] = u_loc;
}

__global__ __launch_bounds__(256) void sde_reduce(const float* __restrict__ partial,
                                                  const float* __restrict__ c2w,
                                                  float* __restrict__ out) {
    int p = blockIdx.x * 256 + threadIdx.x;
    float s = c2w[p];
#pragma unroll
    for (int c = 0; c < 8; c++) s += partial[(size_t)c * NB + p];
    out[p] = s;
}

// --------- unpacked helper (u_pre0 prologue of mid-fallback and sde_ref) ----------
__device__ __forceinline__ void mlp_h2_unpacked(float xx, float xy, float xz,
                                                const float* __restrict__ w0,
                                                const float* __restrict__ c0,
                                                const float* __restrict__ w1,
                                                int lane, f32x4* acc) {
    const int g16 = (lane >> 4) & 3;
    const int l15 = lane & 15;
#pragma unroll
    for (int kk = 0; kk < 2; kk++) {
        bf16x8 af[4];
#pragma unroll
        for (int I = 0; I < 4; I++) {
            uint pk[4];
#pragma unroll
            for (int ep = 0; ep < 4; ep++) {
                float f0 = w1[(kk * 32 + g16 * 8 + 2 * ep + 0) * HD + I * 16 + l15];
                float f1 = w1[(kk * 32 + g16 * 8 + 2 * ep + 1) * HD + I * 16 + l15];
                pk[ep] = (uint)bf16_rne(f0) | ((uint)bf16_rne(f1) << 16);
            }
            uint4 v; v.x = pk[0]; v.y = pk[1]; v.z = pk[2]; v.w = pk[3];
            af[I] = __builtin_bit_cast(bf16x8, v);
        }
        const float* wk = w0 + kk * 32 + g16 * 8;
        float4 wxa = *(const float4*)(wk);
        float4 wxb = *(const float4*)(wk + 4);
        float4 wya = *(const float4*)(wk + HD);
        float4 wyb = *(const float4*)(wk + HD + 4);
        float4 wza = *(const float4*)(wk + 2 * HD);
        float4 wzb = *(const float4*)(wk + 2 * HD + 4);
        const float* ck = c0 + kk * 32 + g16 * 8;
        float4 cva = *(const float4*)(ck);
        float4 cvb = *(const float4*)(ck + 4);
        float p0 = fmaf(xx, wxa.x, fmaf(xy, wya.x, fmaf(xz, wza.x, cva.x)));
        float p1 = fmaf(xx, wxa.y, fmaf(xy, wya.y, fmaf(xz, wza.y, cva.y)));
        float p2 = fmaf(xx, wxa.z, fmaf(xy, wya.z, fmaf(xz, wza.z, cva.z)));
        float p3 = fmaf(xx, wxa.w, fmaf(xy, wya.w, fmaf(xz, wza.w, cva.w)));
        float p4 = fmaf(xx, wxb.x, fmaf(xy, wyb.x, fmaf(xz, wzb.x, cvb.x)));
        float p5 = fmaf(xx, wxb.y, fmaf(xy, wyb.y, fmaf(xz, wzb.y, cvb.y)));
        float p6 = fmaf(xx, wxb.z, fmaf(xy, wyb.z, fmaf(xz, wzb.z, cvb.z)));
        float p7 = fmaf(xx, wxb.w, fmaf(xy, wyb.w, fmaf(xz, wzb.w, cvb.w)));
        uint4 bv;
        bv.x = pack_bf16_trunc(tanh_fast(p0), tanh_fast(p1));
        bv.y = pack_bf16_trunc(tanh_fast(p2), tanh_fast(p3));
        bv.z = pack_bf16_trunc(tanh_fast(p4), tanh_fast(p5));
        bv.w = pack_bf16_trunc(tanh_fast(p6), tanh_fast(p7));
        bf16x8 bf = __builtin_bit_cast(bf16x8, bv);
#pragma unroll
        for (int I = 0; I < 4; I++)
            acc[I] = __builtin_amdgcn_mfma_f32_16x16x32_bf16(af[I], bf, acc[I], 0, 0, 0);
    }
}

// ------------- mid-fallback: R9/R11 monolithic kernel -------------
__global__ __launch_bounds__(256, 4) void sde_fast(
    const float* __restrict__ xt0,
    const float* __restrict__ dBt,
    const float* __restrict__ W0u, const float* __restrict__ b0u,
    const float* __restrict__ W1u, const float* __restrict__ b1u,
    const float* __restrict__ W2u, const float* __restrict__ b2u,
    const float* __restrict__ bg2,
    const uint4* __restrict__ wsB,
    float* __restrict__ out)
{
    const int tid  = threadIdx.x;
    const int lane = tid & 63;
    const int wv   = tid >> 6;
    const int g16  = (lane >> 4) & 3;
    const int l15  = lane & 15;
    const int p    = blockIdx.x * 64 + wv * 16 + l15;

    float xtx = xt0[p * 3 + 0];
    float xty = xt0[p * 3 + 1];
    float xtz = xt0[p * 3 + 2];
    float xix = xtx, xiy = xty, xiz = xtz;
    float g00 = 1.f, g01 = 0.f, g02 = 0.f;
    float g10 = 0.f, g11 = 1.f, g12 = 0.f;
    float g20 = 0.f, g21 = 0.f, g22 = 1.f;

    float u_pre;
    {
        f32x4 acc[4];
#pragma unroll
        for (int I = 0; I < 4; I++) acc[I] = (f32x4){0.f, 0.f, 0.f, 0.f};
        mlp_h2_unpacked(xtx, xty, xtz, W0u, b0u, W1u, lane, acc);
        float pj = 0.f;
#pragma unroll
        for (int I = 0; I < 4; I++) {
            float4 wv2 = *(const float4*)(W2u + I * 16 + g16 * 4);
            float4 cv  = *(const float4*)(b1u + I * 16 + g16 * 4);
            pj = fmaf(tanh_fast(acc[I][0] + cv.x), wv2.x, pj);
            pj = fmaf(tanh_fast(acc[I][1] + cv.y), wv2.y, pj);
            pj = fmaf(tanh_fast(acc[I][2] + cv.z), wv2.z, pj);
            pj = fmaf(tanh_fast(acc[I][3] + cv.w), wv2.w, pj);
        }
        pj += __shfl_xor(pj, 16, 64);
        pj += __shfl_xor(pj, 32, 64);
        u_pre = pj + b2u[0];
    }

#pragma unroll 1
    for (int t = 0; t < NSTEP; t++) {
        const uint4* blob_t = wsB + (size_t)t * TBLK;
        const float* c2     = bg2 + (size_t)t * 3;

        float d  = fmaf(xtx, xtx, fmaf(xty, xty, xtz * xtz));
        float rs = __builtin_amdgcn_rsqf(d);
        float uu = xtz * rs;
        uu = fminf(fmaxf(uu, -0.999999f), 0.999999f);
        float sa = -uu;
        float rho2 = fmaf(xtx, xtx, xty * xty);
        bool hasrho = rho2 > 0.0f;
        float rr = __builtin_amdgcn_rsqf(rho2);
        float cp = hasrho ? (xtx * rr) : 1.0f;
        float sp = hasrho ? (xty * rr) : 0.0f;
        float ca = hasrho ? (rho2 * rr * rs) : 1.4142135e-3f;
        float T00 = cp * ca, T01 = -sp, T02 = cp * sa;
        float T10 = sp * ca, T11 = cp,  T12 = sp * sa;
        float T20 = -sa,               T22 = ca;

        f32x4 a2 = mlp_chain(pack_bf16_trunc(xix, xiy), pack_bf16_trunc(xiz, 1.0f),
                             blob_t, lane, g16);
        float gv0 = a2[0] + c2[0];
        float gv1 = a2[1] + c2[1];
        float gv2 = a2[2] + c2[2];

        float M01 = fmaf(-sp, g00, cp * g01);
        float M11 = fmaf(-sp, g10, cp * g11);
        float M21 = fmaf(-sp, g20, cp * g21);
        float M02 = fmaf(g00, T02, fmaf(g01, T12, g02 * T22));
        float M12 = fmaf(g10, T02, fmaf(g11, T12, g12 * T22));
        float M22 = fmaf(g20, T02, fmaf(g21, T12, g22 * T22));
        float v1 = fmaf(gv0, M01, fmaf(gv1, M11, gv2 * M21));
        float v2 = fmaf(gv0, M02, fmaf(gv1, M12, gv2 * M22));

        const float2 dB = *(const float2*)(dBt + ((size_t)t * NB + p) * 2);
        float dB0 = dB.x, dB1 = dB.y;
        u_pre += fmaf(v1, dB1, -v2 * dB0);

        float s0d, c0d, s1d, c1d;
        sincos_small(dB0, s0d, c0d);
        sincos_small(dB1, s1d, c1d);
        float dx30 = fmaf(c0d, c1d, -1.0f);
        float dx31 = c0d * s1d;
        float dx32 = -s0d;

        float dX0 = fmaf(T00, dx30, fmaf(T01, dx31, T02 * dx32));
        float dX1 = fmaf(T10, dx30, fmaf(T11, dx31, T12 * dx32));
        float dX2 = fmaf(T20, dx30, T22 * dx32);

        xtx += dX0; xty += dX1; xtz += dX2;

        float xi0 = xix + fmaf(g00, dX0, fmaf(g01, dX1, g02 * dX2));
        float xi1 = xiy + fmaf(g10, dX0, fmaf(g11, dX1, g12 * dX2));
        float xi2 = xiz + fmaf(g20, dX0, fmaf(g21, dX1, g22 * dX2));

        float ri2 = fmaf(xi0, xi0, fmaf(xi1, xi1, xi2 * xi2));
        float rs2 = __builtin_amdgcn_rsqf(ri2);
        float ri  = ri2 * rs2;
        bool outb = ri > RB;
        float n0 = xi0 * rs2, n1 = xi1 * rs2, n2 = xi2 * rs2;
        float coefs = outb ? (2.0f * (ri - RB)) : 0.0f;

        xix = fmaf(-coefs, n0, xi0);
        xiy = fmaf(-coefs, n1, xi1);
        xiz = fmaf(-coefs, n2, xi2);

        float mm0 = fmaf(n0, g00, fmaf(n1, g10, n2 * g20));
        float mm1 = fmaf(n0, g01, fmaf(n1, g11, n2 * g21));
        float mm2 = fmaf(n0, g02, fmaf(n1, g12, n2 * g22));
        float tw  = outb ? 2.0f : 0.0f;
        float tn0 = tw * n0, tn1 = tw * n1, tn2 = tw * n2;
        g00 = fmaf(-tn0, mm0, g00);
        g01 = fmaf(-tn0, mm1, g01);
        g02 = fmaf(-tn0, mm2, g02);
        g10 = fmaf(-tn1, mm0, g10);
        g11 = fmaf(-tn1, mm1, g11);
        g12 = fmaf(-tn1, mm2, g12);
        g20 = fmaf(-tn2, mm0, g20);
        g21 = fmaf(-tn2, mm1, g21);
        g22 = fmaf(-tn2, mm2, g22);
    }

    float u_rel = fmaf(xix, xix, fmaf(xiy, xiy, xiz * xiz));
    if (g16 == 0) {
        out[p] = u_pre;
        out[NB + p] = u_rel;
    }
}

// ------------------- final fallback (R3-style, unpacked weights) -------------------
__global__ __launch_bounds__(256, 4) void sde_ref(
    const float* __restrict__ xt0,
    const float* __restrict__ dBt,
    const float* __restrict__ W0u, const float* __restrict__ b0u,
    const float* __restrict__ W1u, const float* __restrict__ b1u,
    const float* __restrict__ W2u, const float* __restrict__ b2u,
    const float* __restrict__ Wg0, const float* __restrict__ bg0,
    const float* __restrict__ Wg1, const float* __restrict__ bg1,
    const float* __restrict__ Wg2, const float* __restrict__ bg2,
    float* __restrict__ out)
{
    const int tid  = threadIdx.x;
    const int lane = tid & 63;
    const int wv   = tid >> 6;
    const int g16  = (lane >> 4) & 3;
    const int l15  = lane & 15;
    const int p    = blockIdx.x * 64 + wv * 16 + l15;

    float xtx = xt0[p * 3 + 0];
    float xty = xt0[p * 3 + 1];
    float xtz = xt0[p * 3 + 2];
    float xix = xtx, xiy = xty, xiz = xtz;
    float g00 = 1.f, g01 = 0.f, g02 = 0.f;
    float g10 = 0.f, g11 = 1.f, g12 = 0.f;
    float g20 = 0.f, g21 = 0.f, g22 = 1.f;

    float u_pre;
    {
        f32x4 acc[4];
#pragma unroll
        for (int I = 0; I < 4; I++) acc[I] = (f32x4){0.f, 0.f, 0.f, 0.f};
        mlp_h2_unpacked(xtx, xty, xtz, W0u, b0u, W1u, lane, acc);
        float pj = 0.f;
#pragma unroll
        for (int I = 0; I < 4; I++) {
            float4 wv2 = *(const float4*)(W2u + I * 16 + g16 * 4);
            float4 cv  = *(const float4*)(b1u + I * 16 + g16 * 4);
            pj = fmaf(tanh_fast(acc[I][0] + cv.x), wv2.x, pj);
            pj = fmaf(tanh_fast(acc[I][1] + cv.y), wv2.y, pj);
            pj = fmaf(tanh_fast(acc[I][2] + cv.z), wv2.z, pj);
            pj = fmaf(tanh_fast(acc[I][3] + cv.w), wv2.w, pj);
        }
        pj += __shfl_xor(pj, 16, 64);
        pj += __shfl_xor(pj, 32, 64);
        u_pre = pj + b2u[0];
    }

#pragma unroll 1
    for (int t = 0; t < NSTEP; t++) {
        const float* w0 = Wg0 + (size_t)t * 3 * HD;
        const float* c0 = bg0 + (size_t)t * HD;
        const float* c1 = bg1 + (size_t)t * HD;
        const float* w2 = Wg2 + (size_t)t * HD * 3;
        const float* c2 = bg2 + (size_t)t * 3;

        float r = sqrtf(fmaf(xtx, xtx, fmaf(xty, xty, xtz * xtz)));
        float uu = xtz / r;
        uu = fminf(fmaxf(uu, -0.999999f), 0.999999f);
        float ca = sqrtf((1.0f - uu) * (1.0f + uu));
        float sa = -uu;
        float rho = sqrtf(fmaf(xtx, xtx, xty * xty));
        float cp = (rho > 0.0f) ? (xtx / rho) : 1.0f;
        float sp = (rho > 0.0f) ? (xty / rho) : 0.0f;
        float T00 = cp * ca, T01 = -sp, T02 = cp * sa;
        float T10 = sp * ca, T11 = cp,  T12 = sp * sa;
        float T20 = -sa,               T22 = ca;

        f32x4 acc[4];
#pragma unroll
        for (int I = 0; I < 4; I++) acc[I] = (f32x4){0.f, 0.f, 0.f, 0.f};
        mlp_h2_unpacked(xix, xiy, xiz, w0, c0, Wg1 + (size_t)t * HD * HD, lane, acc);

        float pj0 = 0.f, pj1 = 0.f, pj2 = 0.f;
#pragma unroll
        for (int I = 0; I < 4; I++) {
            const float* wp = w2 + 3 * (I * 16 + g16 * 4);
            float4 wa = *(const float4*)(wp);
            float4 wb = *(const float4*)(wp + 4);
            float4 wc = *(const float4*)(wp + 8);
            float4 cv = *(const float4*)(c1 + I * 16 + g16 * 4);
            float th0 = tanh_fast(acc[I][0] + cv.x);
            float th1 = tanh_fast(acc[I][1] + cv.y);
            float th2 = tanh_fast(acc[I][2] + cv.z);
            float th3 = tanh_fast(acc[I][3] + cv.w);
            pj0 = fmaf(th0, wa.x, pj0); pj1 = fmaf(th0, wa.y, pj1); pj2 = fmaf(th0, wa.z, pj2);
            pj0 = fmaf(th1, wa.w, pj0); pj1 = fmaf(th1, wb.x, pj1); pj2 = fmaf(th1, wb.y, pj2);
            pj0 = fmaf(th2, wb.z, pj0); pj1 = fmaf(th2, wb.w, pj1); pj2 = fmaf(th2, wc.x, pj2);
            pj0 = fmaf(th3, wc.y, pj0); pj1 = fmaf(th3, wc.z, pj1); pj2 = fmaf(th3, wc.w, pj2);
        }
        pj0 += __shfl_xor(pj0, 16, 64); pj0 += __shfl_xor(pj0, 32, 64);
        pj1 += __shfl_xor(pj1, 16, 64); pj1 += __shfl_xor(pj1, 32, 64);
        pj2 += __shfl_xor(pj2, 16, 64); pj2 += __shfl_xor(pj2, 32, 64);
        float gv0 = pj0 + c2[0];
        float gv1 = pj1 + c2[1];
        float gv2 = pj2 + c2[2];

        float M01 = fmaf(-sp, g00, cp * g01);
        float M11 = fmaf(-sp, g10, cp * g11);
        float M21 = fmaf(-sp, g20, cp * g21);
        float M02 = fmaf(g00, T02, fmaf(g01, T12, g02 * T22));
        float M12 = fmaf(g10, T02, fmaf(g11, T12, g12 * T22));
        float M22 = fmaf(g20, T02, fmaf(g21, T12, g22 * T22));
        float v1 = fmaf(gv0, M01, fmaf(gv1, M11, gv2 * M21));
        float v2 = fmaf(gv0, M02, fmaf(gv1, M12, gv2 * M22));

        const float2 dB = *(const float2*)(dBt + ((size_t)t * NB + p) * 2);
        float dB0 = dB.x, dB1 = dB.y;
        u_pre += fmaf(v1, dB1, -v2 * dB0);

        float s0d, c0d, s1d, c1d;
        __sincosf(dB0, &s0d, &c0d);
        __sincosf(dB1, &s1d, &c1d);
        float dx30 = fmaf(c0d, c1d, -1.0f);
        float dx31 = c0d * s1d;
        float dx32 = -s0d;

        float dX0 = fmaf(T00, dx30, fmaf(T01, dx31, T02 * dx32));
        float dX1 = fmaf(T10, dx30, fmaf(T11, dx31, T12 * dx32));
        float dX2 = fmaf(T20, dx30, T22 * dx32);

        xtx += dX0; xty += dX1; xtz += dX2;

        float xi0 = xix + fmaf(g00, dX0, fmaf(g01, dX1, g02 * dX2));
        float xi1 = xiy + fmaf(g10, dX0, fmaf(g11, dX1, g12 * dX2));
        float xi2 = xiz + fmaf(g20, dX0, fmaf(g21, dX1, g22 * dX2));

        float ri = sqrtf(fmaf(xi0, xi0, fmaf(xi1, xi1, xi2 * xi2)));
        bool outb = ri > RB;
        float n0 = xi0 / ri, n1 = xi1 / ri, n2 = xi2 / ri;
        float coef = 2.0f * (ri - RB);

        xix = outb ? fmaf(-coef, n0, xi0) : xi0;
        xiy = outb ? fmaf(-coef, n1, xi1) : xi1;
        xiz = outb ? fmaf(-coef, n2, xi2) : xi2;

        float mm0 = fmaf(n0, g00, fmaf(n1, g10, n2 * g20));
        float mm1 = fmaf(n0, g01, fmaf(n1, g11, n2 * g21));
        float mm2 = fmaf(n0, g02, fmaf(n1, g12, n2 * g22));
        float tn0 = 2.0f * n0, tn1 = 2.0f * n1, tn2 = 2.0f * n2;
        g00 = outb ? fmaf(-tn0, mm0, g00) : g00;
        g01 = outb ? fmaf(-tn0, mm1, g01) : g01;
        g02 = outb ? fmaf(-tn0, mm2, g02) : g02;
        g10 = outb ? fmaf(-tn1, mm0, g10) : g10;
        g11 = outb ? fmaf(-tn1, mm1, g11) : g11;
        g12 = outb ? fmaf(-tn1, mm2, g12) : g12;
        g20 = outb ? fmaf(-tn2, mm0, g20) : g20;
        g21 = outb ? fmaf(-tn2, mm1, g21) : g21;
        g22 = outb ? fmaf(-tn2, mm2, g22) : g22;
    }

    float u_rel = fmaf(xix, xix, fmaf(xiy, xiy, xiz * xiz));
    if (g16 == 0) {
        out[p] = u_pre;
        out[NB + p] = u_rel;
    }
}

extern "C" void kernel_launch(void* const* d_in, const int* in_sizes, int n_in,
                              void* d_out, int out_size, void* d_ws, size_t ws_size,
                              hipStream_t stream) {
    const float* xt0 = (const float*)d_in[0];
    const float* dBt = (const float*)d_in[1];
    const float* W0u = (const float*)d_in[2];
    const float* b0u = (const float*)d_in[3];
    const float* W1u = (const float*)d_in[4];
    const float* b1u = (const float*)d_in[5];
    const float* W2u = (const float*)d_in[6];
    const float* b2u = (const float*)d_in[7];
    const float* Wg0 = (const float*)d_in[8];
    const float* bg0 = (const float*)d_in[9];
    const float* Wg1 = (const float*)d_in[10];
    const float* bg1 = (const float*)d_in[11];
    const float* Wg2 = (const float*)d_in[12];
    const float* bg2 = (const float*)d_in[13];
    float* out = (float*)d_out;

    const size_t SZ_BLOB = (size_t)(NSTEP + 1) * TBLK * sizeof(uint4);  // ~1.87 MB
    const size_t SZ_XIW  = (size_t)NSTEP * NB * sizeof(uint4);          // 128 MB
    const size_t SZ_C2W  = (size_t)NB * sizeof(float);                  // 256 KB
    const size_t SZ_PART = (size_t)8 * NB * sizeof(float);              // 2 MB

    if (ws_size >= SZ_BLOB + SZ_XIW + SZ_C2W + SZ_PART && d_ws != nullptr) {
        uint4* wsB     = (uint4*)d_ws;
        uint4* xiw     = (uint4*)((char*)d_ws + SZ_BLOB);
        float* c2w     = (float*)((char*)d_ws + SZ_BLOB + SZ_XIW);
        float* partial = (float*)((char*)d_ws + SZ_BLOB + SZ_XIW + SZ_C2W);
        hipLaunchKernelGGL(prep_a1,  dim3(258), dim3(256), 0, stream, Wg1, W1u, wsB);
        hipLaunchKernelGGL(prep_a0,  dim3(129), dim3(256), 0, stream, Wg0, bg0, W0u, b0u, wsB);
        hipLaunchKernelGGL(prep_a2,  dim3(65),  dim3(256), 0, stream, Wg2, W2u, wsB);
        hipLaunchKernelGGL(prep_bias, dim3(65), dim3(256), 0, stream, bg1, b1u, wsB);
        hipLaunchKernelGGL(sde_state, dim3(NB / 256), dim3(256), 0, stream,
                           xt0, dBt, bg2, xiw, c2w, out);
        hipLaunchKernelGGL(sde_mlp, dim3(8192), dim3(256), 0, stream,
                           xt0, (const uint4*)xiw,
                           (const uint4*)wsB, b2u, partial);
        hipLaunchKernelGGL(sde_reduce, dim3(NB / 256), dim3(256), 0, stream,
                           (const float*)partial, (const float*)c2w, out);
    } else if (ws_size >= SZ_BLOB && d_ws != nullptr) {
        uint4* wsB = (uint4*)d_ws;
        hipLaunchKernelGGL(prep_a1,  dim3(258), dim3(256), 0, stream, Wg1, W1u, wsB);
        hipLaunchKernelGGL(prep_a0,  dim3(129), dim3(256), 0, stream, Wg0, bg0, W0u, b0u, wsB);
        hipLaunchKernelGGL(prep_a2,  dim3(65),  dim3(256), 0, stream, Wg2, W2u, wsB);
        hipLaunchKernelGGL(prep_bias, dim3(65), dim3(256), 0, stream, bg1, b1u, wsB);
        hipLaunchKernelGGL(sde_fast, dim3(NB * 4 / 256), dim3(256), 0, stream,
                           xt0, dBt, W0u, b0u, W1u, b1u, W2u, b2u,
                           bg2, (const uint4*)wsB, out);
    } else {
        hipLaunchKernelGGL(sde_ref, dim3(NB * 4 / 256), dim3(256), 0, stream,
                           xt0, dBt, W0u, b0u, W1u, b1u, W2u, b2u,
                           Wg0, bg0, Wg1, bg1, Wg2, bg2, out);
    }
}